// Round 1
// baseline (458.786 us; speedup 1.0000x reference)
//
#include <hip/hip_runtime.h>

#define NCLS 19
#define HW_ (512 * 1024)
#define MIN_KEPT_ 100000LL
#define NSLOT 32
#define COARSE_BINS 1280
#define COARSE_BASE 0x3F333u   // __float_as_uint(0.7f) >> 12

struct Accums {
    unsigned int coarse[COARSE_BINS];   // hist of (bits>>12)-BASE for prob>0.7 (valid only)
    unsigned int fine12[4096];          // rare-path refinement of low 12 bits
    unsigned int slotCnt[NSLOT][NCLS];  // valid count per class
    float        slotSumA[NSLOT][NCLS]; // sum(-logp) over valid
    unsigned int slotCnt07[NSLOT][NCLS];// valid & prob<=0.7 count
    float        slotSum07[NSLOT][NCLS];// sum(-logp) over valid & prob<=0.7
    unsigned int cntR[NCLS];            // rare-path accumulators
    float        sumR[NCLS];
    float        weights[NCLS];
    unsigned int flag;                  // 1 => rare path (kth > 0.7)
    unsigned int sel_prefix;            // bits>>12 of kth
    unsigned int rank_rem;              // 1-based rank within selected coarse bin
    float        threshold;             // exact kth (rare path)
};

__device__ __forceinline__ void accum_pixel(unsigned int* sCnt, float* sSumA,
                                            unsigned int* sCnt07, float* sSum07,
                                            Accums* ws, int lab, float logp, float prob) {
    if (lab < 0 || lab >= NCLS) return;  // ignore_index=255 and any OOB
    float nlp = -logp;
    atomicAdd(&sCnt[lab], 1u);
    atomicAdd(&sSumA[lab], nlp);
    if (prob <= 0.7f) {
        atomicAdd(&sCnt07[lab], 1u);
        atomicAdd(&sSum07[lab], nlp);
    } else {
        unsigned int bits = __float_as_uint(prob);
        int bin = (int)(bits >> 12) - (int)COARSE_BASE;
        bin = bin < 0 ? 0 : (bin >= COARSE_BINS ? COARSE_BINS - 1 : bin);
        atomicAdd(&ws->coarse[bin], 1u);
    }
}

// scalar per-pixel log-softmax (tail + rare-path recompute)
__device__ __forceinline__ bool pix_logp(const float* __restrict__ pred,
                                         const int* __restrict__ targ,
                                         int p, float& logp, float& prob, int& lab) {
    lab = targ[p];
    if (lab < 0 || lab >= NCLS) return false;
    int n = p / HW_;
    int hw = p - n * HW_;
    const float* pb = pred + (size_t)n * NCLS * HW_ + hw;
    float v[NCLS];
    float mx = -3.4e38f, vt = 0.f;
#pragma unroll
    for (int c = 0; c < NCLS; ++c) {
        float x = pb[(size_t)c * HW_];
        v[c] = x;
        mx = fmaxf(mx, x);
        vt = (lab == c) ? x : vt;
    }
    float s = 0.f;
#pragma unroll
    for (int c = 0; c < NCLS; ++c) s += __expf(v[c] - mx);
    logp = vt - (mx + __logf(s));
    prob = __expf(logp);
    return true;
}

__global__ __launch_bounds__(256) void k_main(const float* __restrict__ pred,
                                              const int* __restrict__ targ,
                                              Accums* __restrict__ ws, int P) {
    __shared__ unsigned int sCnt[NCLS], sCnt07[NCLS];
    __shared__ float sSumA[NCLS], sSum07[NCLS];
    if (threadIdx.x < NCLS) {
        sCnt[threadIdx.x] = 0u; sCnt07[threadIdx.x] = 0u;
        sSumA[threadIdx.x] = 0.f; sSum07[threadIdx.x] = 0.f;
    }
    __syncthreads();

    int gid = blockIdx.x * blockDim.x + threadIdx.x;
    int p4 = gid * 4;
    if (p4 < P) {
        if (p4 + 3 < P) {
            int n = p4 / HW_;                 // groups of 4 never cross n (HW_%4==0)
            int hw = p4 - n * HW_;
            const float* pb = pred + (size_t)n * NCLS * HW_ + hw;
            int4 lab = *reinterpret_cast<const int4*>(targ + p4);
            float4 vv[NCLS];
            float4 mx = make_float4(-3.4e38f, -3.4e38f, -3.4e38f, -3.4e38f);
            float4 vt = make_float4(0.f, 0.f, 0.f, 0.f);
#pragma unroll
            for (int c = 0; c < NCLS; ++c) {
                float4 v = *reinterpret_cast<const float4*>(pb + (size_t)c * HW_);
                vv[c] = v;
                mx.x = fmaxf(mx.x, v.x); mx.y = fmaxf(mx.y, v.y);
                mx.z = fmaxf(mx.z, v.z); mx.w = fmaxf(mx.w, v.w);
                vt.x = (lab.x == c) ? v.x : vt.x;
                vt.y = (lab.y == c) ? v.y : vt.y;
                vt.z = (lab.z == c) ? v.z : vt.z;
                vt.w = (lab.w == c) ? v.w : vt.w;
            }
            float4 s = make_float4(0.f, 0.f, 0.f, 0.f);
#pragma unroll
            for (int c = 0; c < NCLS; ++c) {
                s.x += __expf(vv[c].x - mx.x);
                s.y += __expf(vv[c].y - mx.y);
                s.z += __expf(vv[c].z - mx.z);
                s.w += __expf(vv[c].w - mx.w);
            }
            {
                float lp = vt.x - (mx.x + __logf(s.x));
                accum_pixel(sCnt, sSumA, sCnt07, sSum07, ws, lab.x, lp, __expf(lp));
                lp = vt.y - (mx.y + __logf(s.y));
                accum_pixel(sCnt, sSumA, sCnt07, sSum07, ws, lab.y, lp, __expf(lp));
                lp = vt.z - (mx.z + __logf(s.z));
                accum_pixel(sCnt, sSumA, sCnt07, sSum07, ws, lab.z, lp, __expf(lp));
                lp = vt.w - (mx.w + __logf(s.w));
                accum_pixel(sCnt, sSumA, sCnt07, sSum07, ws, lab.w, lp, __expf(lp));
            }
        } else {
            for (int j = 0; j < 4; ++j) {
                int p = p4 + j;
                if (p >= P) break;
                float lp, pr; int lb;
                if (pix_logp(pred, targ, p, lp, pr, lb))
                    accum_pixel(sCnt, sSumA, sCnt07, sSum07, ws, lb, lp, pr);
            }
        }
    }
    __syncthreads();
    int slot = blockIdx.x & (NSLOT - 1);
    if (threadIdx.x < NCLS) {
        int i = threadIdx.x;
        if (sCnt[i])          atomicAdd(&ws->slotCnt[slot][i], sCnt[i]);
        if (sSumA[i] != 0.f)  atomicAdd(&ws->slotSumA[slot][i], sSumA[i]);
        if (sCnt07[i])        atomicAdd(&ws->slotCnt07[slot][i], sCnt07[i]);
        if (sSum07[i] != 0.f) atomicAdd(&ws->slotSum07[slot][i], sSum07[i]);
    }
}

__global__ void k_finalize(Accums* __restrict__ ws, float* __restrict__ out) {
    __shared__ unsigned int cnt[NCLS], c07[NCLS];
    __shared__ float sA[NCLS], s07[NCLS];
    int t = threadIdx.x;
    if (t < NCLS) {
        unsigned int c = 0, c7 = 0; float a = 0.f, b = 0.f;
        for (int s = 0; s < NSLOT; ++s) {
            c  += ws->slotCnt[s][t];   a += ws->slotSumA[s][t];
            c7 += ws->slotCnt07[s][t]; b += ws->slotSum07[s][t];
        }
        cnt[t] = c; c07[t] = c7; sA[t] = a; s07[t] = b;
    }
    __syncthreads();
    if (t != 0) return;

    long long nv = 0, c7tot = 0;
    for (int c = 0; c < NCLS; ++c) { nv += cnt[c]; c7tot += c07[c]; }

    // class weights: median(present counts)/count, else 1.0
    float w[NCLS];
    {
        float vals[NCLS]; int m = 0;
        for (int c = 0; c < NCLS; ++c)
            if (cnt[c] > 0) vals[m++] = (float)cnt[c];
        for (int i = 1; i < m; ++i) {          // insertion sort (<=19 elems)
            float x = vals[i]; int j = i - 1;
            while (j >= 0 && vals[j] > x) { vals[j + 1] = vals[j]; --j; }
            vals[j + 1] = x;
        }
        float med = 1.f;
        if (m > 0) med = (m & 1) ? vals[m / 2] : 0.5f * (vals[m / 2 - 1] + vals[m / 2]);
        for (int c = 0; c < NCLS; ++c) {
            w[c] = (cnt[c] > 0) ? med / fmaxf((float)cnt[c], 1.f) : 1.f;
            ws->weights[c] = w[c];
        }
    }

    if (nv == 0) { out[0] = 0.f; return; }     // flag stays 0

    bool do_ohem = nv > MIN_KEPT_;
    long long kkeep = nv < MIN_KEPT_ ? nv : MIN_KEPT_;

    float S = 0.f, W = 0.f;
    if (!do_ohem) {
        for (int c = 0; c < NCLS; ++c) { S += w[c] * sA[c]; W += w[c] * (float)cnt[c]; }
    } else if (c7tot >= kkeep) {               // kth <= 0.7  => threshold = 0.7
        for (int c = 0; c < NCLS; ++c) { S += w[c] * s07[c]; W += w[c] * (float)c07[c]; }
    } else {                                   // rare: threshold = kth > 0.7
        unsigned int r = (unsigned int)(kkeep - c7tot);   // 1-based rank among probs>0.7
        unsigned int cum = 0, before = 0; int bsel = COARSE_BINS - 1;
        for (int i = 0; i < COARSE_BINS; ++i) {
            unsigned int nc = cum + ws->coarse[i];
            if (nc >= r) { bsel = i; before = cum; break; }
            cum = nc;
        }
        ws->sel_prefix = COARSE_BASE + (unsigned int)bsel;
        ws->rank_rem = r - before;
        ws->flag = 1u;
        return;                                // final loss written by k_rare_final
    }
    out[0] = S / fmaxf(W, 1e-12f);
}

__global__ void k_refine(const float* __restrict__ pred, const int* __restrict__ targ,
                         Accums* __restrict__ ws, int P) {
    __shared__ unsigned int flag; __shared__ unsigned int prefix;
    if (threadIdx.x == 0) { flag = ws->flag; prefix = ws->sel_prefix; }
    __syncthreads();
    if (!flag) return;
    int stride = gridDim.x * blockDim.x;
    for (int p = blockIdx.x * blockDim.x + threadIdx.x; p < P; p += stride) {
        float lp, pr; int lb;
        if (!pix_logp(pred, targ, p, lp, pr, lb)) continue;
        if (pr > 0.7f) {
            unsigned int bits = __float_as_uint(pr);
            if ((bits >> 12) == prefix) atomicAdd(&ws->fine12[bits & 0xFFFu], 1u);
        }
    }
}

__global__ void k_pick(Accums* __restrict__ ws) {
    if (threadIdx.x != 0) return;
    if (!ws->flag) return;
    unsigned int r = ws->rank_rem, cum = 0, low = 4095;
    for (unsigned int i = 0; i < 4096; ++i) {
        cum += ws->fine12[i];
        if (cum >= r) { low = i; break; }
    }
    ws->threshold = __uint_as_float((ws->sel_prefix << 12) | low);
}

__global__ void k_rare_accum(const float* __restrict__ pred, const int* __restrict__ targ,
                             Accums* __restrict__ ws, int P) {
    __shared__ unsigned int flag; __shared__ float thr;
    if (threadIdx.x == 0) { flag = ws->flag; thr = ws->threshold; }
    __syncthreads();
    if (!flag) return;
    int stride = gridDim.x * blockDim.x;
    for (int p = blockIdx.x * blockDim.x + threadIdx.x; p < P; p += stride) {
        float lp, pr; int lb;
        if (!pix_logp(pred, targ, p, lp, pr, lb)) continue;
        if (pr <= thr) {
            atomicAdd(&ws->cntR[lb], 1u);
            atomicAdd(&ws->sumR[lb], -lp);
        }
    }
}

__global__ void k_rare_final(Accums* __restrict__ ws, float* __restrict__ out) {
    if (threadIdx.x != 0) return;
    if (!ws->flag) return;
    float S = 0.f, W = 0.f;
    for (int c = 0; c < NCLS; ++c) {
        S += ws->weights[c] * ws->sumR[c];
        W += ws->weights[c] * (float)ws->cntR[c];
    }
    out[0] = S / fmaxf(W, 1e-12f);
}

extern "C" void kernel_launch(void* const* d_in, const int* in_sizes, int n_in,
                              void* d_out, int out_size, void* d_ws, size_t ws_size,
                              hipStream_t stream) {
    const float* pred = (const float*)d_in[0];
    const int*   targ = (const int*)d_in[1];
    float*       out  = (float*)d_out;
    int P = in_sizes[1];                 // N*H*W pixels
    Accums* ws = (Accums*)d_ws;

    hipMemsetAsync(d_ws, 0, sizeof(Accums), stream);
    hipMemsetAsync(d_out, 0, (size_t)out_size * sizeof(float), stream);

    int blocks = (P + 1023) / 1024;      // 256 threads x 4 pixels
    k_main<<<blocks, 256, 0, stream>>>(pred, targ, ws, P);
    k_finalize<<<1, 64, 0, stream>>>(ws, out);
    // rare-path kernels: early-exit (one flag load per block) when threshold == 0.7
    k_refine<<<2048, 256, 0, stream>>>(pred, targ, ws, P);
    k_pick<<<1, 64, 0, stream>>>(ws);
    k_rare_accum<<<2048, 256, 0, stream>>>(pred, targ, ws, P);
    k_rare_final<<<1, 64, 0, stream>>>(ws, out);
}

// Round 2
// 447.200 us; speedup vs baseline: 1.0259x; 1.0259x over previous
//
#include <hip/hip_runtime.h>

#define NCLS 19
#define HW_ (512 * 1024)
#define MIN_KEPT_ 100000LL
#define NSLOT 32
#define COARSE_BINS 1280
#define COARSE_BASE 0x3F333u   // __float_as_uint(0.7f) >> 12

struct Accums {
    unsigned int coarse[COARSE_BINS];   // hist of (bits>>12)-BASE for prob>0.7 (valid only)
    unsigned int fine12[4096];          // rare-path refinement of low 12 bits
    unsigned int slotCnt[NSLOT][NCLS];  // valid count per class
    float        slotSumA[NSLOT][NCLS]; // sum(-logp) over valid
    unsigned int slotCntG[NSLOT][NCLS]; // valid & prob>0.7 count   (RARE side)
    float        slotSumG[NSLOT][NCLS]; // sum(-logp) over valid & prob>0.7
    unsigned int cntR[NCLS];            // rare-path accumulators
    float        sumR[NCLS];
    float        weights[NCLS];
    unsigned int flag;                  // 1 => rare path (kth > 0.7)
    unsigned int sel_prefix;            // bits>>12 of kth
    unsigned int rank_rem;              // 1-based rank within selected coarse bin
    float        threshold;             // exact kth (rare path)
    unsigned int done1, done2;          // block-completion counters (refine / rare)
};

__device__ __forceinline__ unsigned int aloadu(const unsigned int* p) {
    return __hip_atomic_load(p, __ATOMIC_RELAXED, __HIP_MEMORY_SCOPE_AGENT);
}
__device__ __forceinline__ float aloadf(const float* p) {
    return __hip_atomic_load(p, __ATOMIC_RELAXED, __HIP_MEMORY_SCOPE_AGENT);
}

__device__ __forceinline__ void accum_pixel(unsigned int* sCnt, float* sSumA,
                                            unsigned int* sCntG, float* sSumG,
                                            Accums* ws, int lab, float logp, float prob) {
    if (lab < 0 || lab >= NCLS) return;  // ignore_index=255 and any OOB
    float nlp = -logp;
    atomicAdd(&sCnt[lab], 1u);
    atomicAdd(&sSumA[lab], nlp);
    if (prob > 0.7f) {                   // RARE (~<1% of pixels)
        atomicAdd(&sCntG[lab], 1u);
        atomicAdd(&sSumG[lab], nlp);
        unsigned int bits = __float_as_uint(prob);
        int bin = (int)(bits >> 12) - (int)COARSE_BASE;
        bin = bin < 0 ? 0 : (bin >= COARSE_BINS ? COARSE_BINS - 1 : bin);
        atomicAdd(&ws->coarse[bin], 1u);
    }
}

// scalar per-pixel log-softmax (tail + rare-path recompute)
__device__ __forceinline__ bool pix_logp(const float* __restrict__ pred,
                                         const int* __restrict__ targ,
                                         int p, float& logp, float& prob, int& lab) {
    lab = targ[p];
    if (lab < 0 || lab >= NCLS) return false;
    int n = p / HW_;
    int hw = p - n * HW_;
    const float* pb = pred + (size_t)n * NCLS * HW_ + hw;
    float v[NCLS];
    float mx = -3.4e38f, vt = 0.f;
#pragma unroll
    for (int c = 0; c < NCLS; ++c) {
        float x = pb[(size_t)c * HW_];
        v[c] = x;
        mx = fmaxf(mx, x);
        vt = (lab == c) ? x : vt;
    }
    float s = 0.f;
#pragma unroll
    for (int c = 0; c < NCLS; ++c) s += __expf(v[c] - mx);
    logp = vt - (mx + __logf(s));
    prob = __expf(logp);
    return true;
}

__global__ __launch_bounds__(256) void k_main(const float* __restrict__ pred,
                                              const int* __restrict__ targ,
                                              Accums* __restrict__ ws, int P) {
    __shared__ unsigned int sCnt[NCLS], sCntG[NCLS];
    __shared__ float sSumA[NCLS], sSumG[NCLS];
    if (threadIdx.x < NCLS) {
        sCnt[threadIdx.x] = 0u; sCntG[threadIdx.x] = 0u;
        sSumA[threadIdx.x] = 0.f; sSumG[threadIdx.x] = 0.f;
    }
    __syncthreads();

    int gid = blockIdx.x * blockDim.x + threadIdx.x;
    int p4 = gid * 4;
    if (p4 < P) {
        if (p4 + 3 < P) {
            int n = p4 / HW_;                 // groups of 4 never cross n (HW_%4==0)
            int hw = p4 - n * HW_;
            const float* pb = pred + (size_t)n * NCLS * HW_ + hw;
            int4 lab = *reinterpret_cast<const int4*>(targ + p4);
            float4 vv[NCLS];
            float4 mx = make_float4(-3.4e38f, -3.4e38f, -3.4e38f, -3.4e38f);
            float4 vt = make_float4(0.f, 0.f, 0.f, 0.f);
#pragma unroll
            for (int c = 0; c < NCLS; ++c) {
                float4 v = *reinterpret_cast<const float4*>(pb + (size_t)c * HW_);
                vv[c] = v;
                mx.x = fmaxf(mx.x, v.x); mx.y = fmaxf(mx.y, v.y);
                mx.z = fmaxf(mx.z, v.z); mx.w = fmaxf(mx.w, v.w);
                vt.x = (lab.x == c) ? v.x : vt.x;
                vt.y = (lab.y == c) ? v.y : vt.y;
                vt.z = (lab.z == c) ? v.z : vt.z;
                vt.w = (lab.w == c) ? v.w : vt.w;
            }
            float4 s = make_float4(0.f, 0.f, 0.f, 0.f);
#pragma unroll
            for (int c = 0; c < NCLS; ++c) {
                s.x += __expf(vv[c].x - mx.x);
                s.y += __expf(vv[c].y - mx.y);
                s.z += __expf(vv[c].z - mx.z);
                s.w += __expf(vv[c].w - mx.w);
            }
            {
                float lp = vt.x - (mx.x + __logf(s.x));
                accum_pixel(sCnt, sSumA, sCntG, sSumG, ws, lab.x, lp, __expf(lp));
                lp = vt.y - (mx.y + __logf(s.y));
                accum_pixel(sCnt, sSumA, sCntG, sSumG, ws, lab.y, lp, __expf(lp));
                lp = vt.z - (mx.z + __logf(s.z));
                accum_pixel(sCnt, sSumA, sCntG, sSumG, ws, lab.z, lp, __expf(lp));
                lp = vt.w - (mx.w + __logf(s.w));
                accum_pixel(sCnt, sSumA, sCntG, sSumG, ws, lab.w, lp, __expf(lp));
            }
        } else {
            for (int j = 0; j < 4; ++j) {
                int p = p4 + j;
                if (p >= P) break;
                float lp, pr; int lb;
                if (pix_logp(pred, targ, p, lp, pr, lb))
                    accum_pixel(sCnt, sSumA, sCntG, sSumG, ws, lb, lp, pr);
            }
        }
    }
    __syncthreads();
    int slot = blockIdx.x & (NSLOT - 1);
    if (threadIdx.x < NCLS) {
        int i = threadIdx.x;
        if (sCnt[i])          atomicAdd(&ws->slotCnt[slot][i], sCnt[i]);
        if (sSumA[i] != 0.f)  atomicAdd(&ws->slotSumA[slot][i], sSumA[i]);
        if (sCntG[i])         atomicAdd(&ws->slotCntG[slot][i], sCntG[i]);
        if (sSumG[i] != 0.f)  atomicAdd(&ws->slotSumG[slot][i], sSumG[i]);
    }
}

__global__ void k_finalize(Accums* __restrict__ ws, float* __restrict__ out) {
    __shared__ unsigned int cnt[NCLS], cG[NCLS];
    __shared__ float sA[NCLS], sG[NCLS];
    int t = threadIdx.x;
    if (t < NCLS) {
        unsigned int c = 0, cg = 0; float a = 0.f, b = 0.f;
        for (int s = 0; s < NSLOT; ++s) {
            c  += ws->slotCnt[s][t];  a += ws->slotSumA[s][t];
            cg += ws->slotCntG[s][t]; b += ws->slotSumG[s][t];
        }
        cnt[t] = c; cG[t] = cg; sA[t] = a; sG[t] = b;
    }
    __syncthreads();
    if (t != 0) return;

    long long nv = 0, c7tot = 0;
    for (int c = 0; c < NCLS; ++c) { nv += cnt[c]; c7tot += (long long)(cnt[c] - cG[c]); }

    // class weights: median(present counts)/count, else 1.0
    float w[NCLS];
    {
        float vals[NCLS]; int m = 0;
        for (int c = 0; c < NCLS; ++c)
            if (cnt[c] > 0) vals[m++] = (float)cnt[c];
        for (int i = 1; i < m; ++i) {          // insertion sort (<=19 elems)
            float x = vals[i]; int j = i - 1;
            while (j >= 0 && vals[j] > x) { vals[j + 1] = vals[j]; --j; }
            vals[j + 1] = x;
        }
        float med = 1.f;
        if (m > 0) med = (m & 1) ? vals[m / 2] : 0.5f * (vals[m / 2 - 1] + vals[m / 2]);
        for (int c = 0; c < NCLS; ++c) {
            w[c] = (cnt[c] > 0) ? med / fmaxf((float)cnt[c], 1.f) : 1.f;
            ws->weights[c] = w[c];
        }
    }

    if (nv == 0) { out[0] = 0.f; return; }     // flag stays 0

    bool do_ohem = nv > MIN_KEPT_;
    long long kkeep = nv < MIN_KEPT_ ? nv : MIN_KEPT_;

    float S = 0.f, W = 0.f;
    if (!do_ohem) {
        for (int c = 0; c < NCLS; ++c) { S += w[c] * sA[c]; W += w[c] * (float)cnt[c]; }
    } else if (c7tot >= kkeep) {               // kth <= 0.7  => threshold = 0.7
        for (int c = 0; c < NCLS; ++c) {
            S += w[c] * (sA[c] - sG[c]);
            W += w[c] * (float)(cnt[c] - cG[c]);
        }
    } else {                                   // rare: threshold = kth > 0.7
        unsigned int r = (unsigned int)(kkeep - c7tot);   // 1-based rank among probs>0.7
        unsigned int cum = 0, before = 0; int bsel = COARSE_BINS - 1;
        for (int i = 0; i < COARSE_BINS; ++i) {
            unsigned int nc = cum + ws->coarse[i];
            if (nc >= r) { bsel = i; before = cum; break; }
            cum = nc;
        }
        ws->sel_prefix = COARSE_BASE + (unsigned int)bsel;
        ws->rank_rem = r - before;
        ws->flag = 1u;
        return;                                // final loss written by k_rare's last block
    }
    out[0] = S / fmaxf(W, 1e-12f);
}

// rare path: fine histogram over low 12 bits of prefix-matching probs; last block picks kth
__global__ void k_refine(const float* __restrict__ pred, const int* __restrict__ targ,
                         Accums* __restrict__ ws, int P) {
    __shared__ unsigned int flag; __shared__ unsigned int prefix; __shared__ int sIsLast;
    if (threadIdx.x == 0) { flag = ws->flag; prefix = ws->sel_prefix; }
    __syncthreads();
    if (!flag) return;
    int stride = gridDim.x * blockDim.x;
    for (int p = blockIdx.x * blockDim.x + threadIdx.x; p < P; p += stride) {
        float lp, pr; int lb;
        if (!pix_logp(pred, targ, p, lp, pr, lb)) continue;
        if (pr > 0.7f) {
            unsigned int bits = __float_as_uint(pr);
            if ((bits >> 12) == prefix) atomicAdd(&ws->fine12[bits & 0xFFFu], 1u);
        }
    }
    __syncthreads();
    if (threadIdx.x == 0) {
        __threadfence();
        unsigned int old = __hip_atomic_fetch_add(&ws->done1, 1u, __ATOMIC_ACQ_REL,
                                                  __HIP_MEMORY_SCOPE_AGENT);
        sIsLast = (old == gridDim.x - 1);
    }
    __syncthreads();
    if (sIsLast && threadIdx.x == 0) {
        unsigned int r = ws->rank_rem, cum = 0, low = 4095;
        for (unsigned int i = 0; i < 4096; ++i) {
            cum += aloadu(&ws->fine12[i]);
            if (cum >= r) { low = i; break; }
        }
        ws->threshold = __uint_as_float((prefix << 12) | low);
    }
}

// rare path: re-accumulate kept pixels with exact threshold; last block writes loss
__global__ void k_rare(const float* __restrict__ pred, const int* __restrict__ targ,
                       Accums* __restrict__ ws, float* __restrict__ out, int P) {
    __shared__ unsigned int flag; __shared__ float thr; __shared__ int sIsLast;
    if (threadIdx.x == 0) { flag = ws->flag; thr = ws->threshold; }
    __syncthreads();
    if (!flag) return;
    int stride = gridDim.x * blockDim.x;
    for (int p = blockIdx.x * blockDim.x + threadIdx.x; p < P; p += stride) {
        float lp, pr; int lb;
        if (!pix_logp(pred, targ, p, lp, pr, lb)) continue;
        if (pr <= thr) {
            atomicAdd(&ws->cntR[lb], 1u);
            atomicAdd(&ws->sumR[lb], -lp);
        }
    }
    __syncthreads();
    if (threadIdx.x == 0) {
        __threadfence();
        unsigned int old = __hip_atomic_fetch_add(&ws->done2, 1u, __ATOMIC_ACQ_REL,
                                                  __HIP_MEMORY_SCOPE_AGENT);
        sIsLast = (old == gridDim.x - 1);
    }
    __syncthreads();
    if (sIsLast && threadIdx.x == 0) {
        float S = 0.f, W = 0.f;
        for (int c = 0; c < NCLS; ++c) {
            S += ws->weights[c] * aloadf(&ws->sumR[c]);
            W += ws->weights[c] * (float)aloadu(&ws->cntR[c]);
        }
        out[0] = S / fmaxf(W, 1e-12f);
    }
}

extern "C" void kernel_launch(void* const* d_in, const int* in_sizes, int n_in,
                              void* d_out, int out_size, void* d_ws, size_t ws_size,
                              hipStream_t stream) {
    const float* pred = (const float*)d_in[0];
    const int*   targ = (const int*)d_in[1];
    float*       out  = (float*)d_out;
    int P = in_sizes[1];                 // N*H*W pixels
    Accums* ws = (Accums*)d_ws;

    hipMemsetAsync(d_ws, 0, sizeof(Accums), stream);

    int blocks = (P + 1023) / 1024;      // 256 threads x 4 pixels
    k_main<<<blocks, 256, 0, stream>>>(pred, targ, ws, P);
    k_finalize<<<1, 64, 0, stream>>>(ws, out);   // writes out[0] unless rare path
    // rare-path kernels: early-exit (one flag load per block) when threshold == 0.7
    k_refine<<<1024, 256, 0, stream>>>(pred, targ, ws, P);
    k_rare<<<1024, 256, 0, stream>>>(pred, targ, ws, out, P);
}